// Round 6
// baseline (1581.361 us; speedup 1.0000x reference)
//
#include <hip/hip_runtime.h>
#include <hip/hip_bf16.h>
#include <hip/hip_cooperative_groups.h>

namespace cg = cooperative_groups;

constexpr int N_NODES = 100000;
constexpr int N_EDGES = 3200000;
constexpr int N_PAIRS = 500000;
constexpr int D       = 256;
constexpr int NCHUNK  = 16;
constexpr int CHUNK_NODES = N_NODES / NCHUNK;   // 6250
constexpr int GATHER_BLOCKS = 512;              // 4 waves each -> 2048 waves
constexpr int N_WAVES = GATHER_BLOCKS * 4;      // 2048
constexpr int NPW     = 49;                     // nodes per wave
constexpr int NPAD    = N_WAVES * NPW;          // 100352 padded nodes
constexpr int SEGN    = NCHUNK * NPAD;          // 1,605,632 = 1568*1024

using frag_ab = __attribute__((ext_vector_type(8))) short;
using frag_cd = __attribute__((ext_vector_type(4))) float;
typedef unsigned short ushort8 __attribute__((ext_vector_type(8)));

static __device__ __forceinline__ float b2f(unsigned short u) {
  return __uint_as_float(((unsigned)u) << 16);
}
static __device__ __forceinline__ unsigned short f2bf(float f) {
  unsigned u = __float_as_uint(f);
  unsigned r = (u + 0x7fff + ((u >> 16) & 1)) >> 16;   // RNE
  return (unsigned short)r;
}

// ---------------------------------------------------------------------------
__global__ void zero_ints(int* __restrict__ p, int n) {
  int i = blockIdx.x * blockDim.x + threadIdx.x;
  if (i < n) p[i] = 0;
}

__global__ void f32_to_bf16(const float4* __restrict__ in, ushort4* __restrict__ out, int n4) {
  int i = blockIdx.x * blockDim.x + threadIdx.x;
  int stride = gridDim.x * blockDim.x;
  for (; i < n4; i += stride) {
    const float4 v = in[i];
    ushort4 o;
    o.x = f2bf(v.x); o.y = f2bf(v.y); o.z = f2bf(v.z); o.w = f2bf(v.w);
    out[i] = o;
  }
}

// cnt[chunk(src)*NPAD + dst]++   (chunk-major layout)
__global__ void hist_cm_kernel(const int* __restrict__ ei, int* __restrict__ cnt) {
  int i = blockIdx.x * blockDim.x + threadIdx.x;
  if (i < N_EDGES) {
    const int src = ei[i];
    const int dst = ei[N_EDGES + i];
    atomicAdd(&cnt[(src / CHUNK_NODES) * NPAD + dst], 1);
  }
}

// --- hierarchical exclusive scan over SEGN ints -----------------------------
// k1: per-1024-block local exclusive scan, emit block totals
__global__ __launch_bounds__(1024) void scan_block_k(const int* __restrict__ in,
                                                     int* __restrict__ out,
                                                     int* __restrict__ bsum) {
  __shared__ int wsum[16];
  const int t = threadIdx.x, lane = t & 63, w = t >> 6;
  const int gid = blockIdx.x * 1024 + t;
  const int v = in[gid];
  int s = v;
#pragma unroll
  for (int off = 1; off < 64; off <<= 1) {
    int u = __shfl_up(s, off, 64);
    if (lane >= off) s += u;
  }
  if (lane == 63) wsum[w] = s;
  __syncthreads();
  if (t < 16) {
    int ws = wsum[t];
#pragma unroll
    for (int off = 1; off < 16; off <<= 1) {
      int u = __shfl_up(ws, off, 64);
      if (lane >= off) ws += u;
    }
    wsum[t] = ws;
  }
  __syncthreads();
  const int wpre = (w == 0) ? 0 : wsum[w - 1];
  out[gid] = wpre + s - v;               // block-local exclusive
  if (t == 1023) bsum[blockIdx.x] = wsum[15];
}

// k2: single-block exclusive scan (n small) — also used nowhere else now
__global__ __launch_bounds__(1024) void scan_kernel(const int* __restrict__ counts,
                                                    int* __restrict__ cursor, int n) {
  __shared__ int wsum[16];
  __shared__ int carry;
  const int t = threadIdx.x, lane = t & 63, w = t >> 6;
  if (t == 0) carry = 0;
  __syncthreads();
  for (int base = 0; base < n; base += 1024) {
    int v = (base + t < n) ? counts[base + t] : 0;
    int s = v;
#pragma unroll
    for (int off = 1; off < 64; off <<= 1) {
      int u = __shfl_up(s, off, 64);
      if (lane >= off) s += u;
    }
    if (lane == 63) wsum[w] = s;
    __syncthreads();
    if (t < 16) {
      int ws = wsum[t];
#pragma unroll
      for (int off = 1; off < 16; off <<= 1) {
        int u = __shfl_up(ws, off, 64);
        if (lane >= off) ws += u;
      }
      wsum[t] = ws;
    }
    __syncthreads();
    const int wpre = (w == 0) ? 0 : wsum[w - 1];
    if (base + t < n) cursor[base + t] = carry + wpre + s - v;
    __syncthreads();
    if (t == 0) carry += wsum[15];
    __syncthreads();
  }
}

// k3: add block offsets; write sentinel
__global__ __launch_bounds__(1024) void scan_add_k(int* __restrict__ p2s,
                                                   const int* __restrict__ bsum2) {
  const int gid = blockIdx.x * 1024 + threadIdx.x;
  p2s[gid] += bsum2[gid >> 10];
  if (gid == 0) p2s[SEGN] = N_EDGES;
}

// XCD-partitioned fill into chunk-major csr
constexpr int FILL_SEG = 4096;
__global__ __launch_bounds__(256) void fill_cm_kernel(const int* __restrict__ ei,
                                                      int* __restrict__ pos,
                                                      int* __restrict__ csr) {
  const int range = blockIdx.x & 7;
  const int seg   = blockIdx.x >> 3;
  const int base  = seg * FILL_SEG;
  const int lo = range * 12500, hi = lo + 12500;
#pragma unroll
  for (int j = 0; j < FILL_SEG / 256; ++j) {
    const int i = base + j * 256 + threadIdx.x;
    if (i < N_EDGES) {
      const int dst = ei[N_EDGES + i];
      if (dst >= lo && dst < hi) {
        const int src = ei[i];
        const int p = atomicAdd(&pos[(src / CHUNK_NODES) * NPAD + dst], 1);
        csr[p] = src;
      }
    }
  }
}

// ---------------------------------------------------------------------------
// Phased persistent gather. 2048 waves x 49 nodes, accumulators in registers
// (49 x f32x4 per lane). 16 chunk phases; during phase c all reads hit the
// 3.2 MB src-chunk c (fits each XCD's 4 MB L2). grid.sync() between phases is
// timing-only (no data exchanged) -> correctness independent of sync.
// ---------------------------------------------------------------------------
template <bool SYNC>
__global__ __launch_bounds__(256, 2) void gather_phased(const ushort* __restrict__ x,
                                                        const int* __restrict__ csr,
                                                        const int* __restrict__ p2s,
                                                        ushort* __restrict__ out) {
  const int wave = blockIdx.x * 4 + (threadIdx.x >> 6);
  const int lane = threadIdx.x & 63;
  const int n0 = wave * NPW;

  float4 acc[NPW];
#pragma unroll
  for (int i = 0; i < NPW; ++i) {
    const int node = n0 + i;
    if (node < N_NODES) {
      const ushort4 v = *reinterpret_cast<const ushort4*>(x + (size_t)node * D + lane * 4);
      acc[i].x = b2f(v.x); acc[i].y = b2f(v.y); acc[i].z = b2f(v.z); acc[i].w = b2f(v.w);
    } else {
      acc[i].x = acc[i].y = acc[i].z = acc[i].w = 0.f;
    }
  }

  for (int c = 0; c < NCHUNK; ++c) {
    // lanes 0..49 hold segment boundaries for this wave's nodes in phase c
    const int li = (lane <= NPW) ? lane : NPW;
    const int segv = p2s[c * NPAD + n0 + li];
    const int base = __shfl(segv, 0, 64);
    const int wend = __shfl(segv, NPW, 64);
    const int nE = wend - base;
    // prefetch up to 192 edge indices into 3 regs (coalesced)
    const int e0 = (lane      < nE) ? csr[base + lane]       : 0;
    const int e1 = (lane + 64 < nE) ? csr[base + lane + 64]  : 0;
    const int e2 = (lane + 128 < nE) ? csr[base + lane + 128] : 0;

#pragma unroll
    for (int i = 0; i < NPW; ++i) {
      const int s = __shfl(segv, i, 64);
      const int e = __shfl(segv, i + 1, 64);
      int o = s;
      while (o + 1 < e) {
        const int k0 = o - base, k1 = k0 + 1;
        int i0, i1;
        if (k1 < 192) {
          i0 = (k0 < 64) ? __shfl(e0, k0, 64) : (k0 < 128) ? __shfl(e1, k0 & 63, 64) : __shfl(e2, k0 & 63, 64);
          i1 = (k1 < 64) ? __shfl(e0, k1, 64) : (k1 < 128) ? __shfl(e1, k1 & 63, 64) : __shfl(e2, k1 & 63, 64);
        } else { i0 = csr[o]; i1 = csr[o + 1]; }
        const ushort4 v0 = *reinterpret_cast<const ushort4*>(x + (size_t)i0 * D + lane * 4);
        const ushort4 v1 = *reinterpret_cast<const ushort4*>(x + (size_t)i1 * D + lane * 4);
        acc[i].x += b2f(v0.x) + b2f(v1.x);
        acc[i].y += b2f(v0.y) + b2f(v1.y);
        acc[i].z += b2f(v0.z) + b2f(v1.z);
        acc[i].w += b2f(v0.w) + b2f(v1.w);
        o += 2;
      }
      if (o < e) {
        const int k = o - base;
        int is;
        if (k < 192) {
          is = (k < 64) ? __shfl(e0, k, 64) : (k < 128) ? __shfl(e1, k & 63, 64) : __shfl(e2, k & 63, 64);
        } else is = csr[o];
        const ushort4 v = *reinterpret_cast<const ushort4*>(x + (size_t)is * D + lane * 4);
        acc[i].x += b2f(v.x); acc[i].y += b2f(v.y); acc[i].z += b2f(v.z); acc[i].w += b2f(v.w);
      }
    }
    if constexpr (SYNC) {
      if (c + 1 < NCHUNK) cg::this_grid().sync();
    }
  }

#pragma unroll
  for (int i = 0; i < NPW; ++i) {
    const int node = n0 + i;
    if (node < N_NODES) {
      ushort4 ov;
      ov.x = f2bf(acc[i].x); ov.y = f2bf(acc[i].y); ov.z = f2bf(acc[i].z); ov.w = f2bf(acc[i].w);
      *reinterpret_cast<ushort4*>(out + (size_t)node * D + lane * 4) = ov;
    }
  }
}

// ---------------------------------------------------------------------------
// C[r][c] = relu( sum_k A[r][k]*W[c][k] + bias[c] ), bf16 in / bf16 out.
// 4 waves, 64x64 tile, K=256 staged in LDS with XOR swizzle.
// ---------------------------------------------------------------------------
__global__ __launch_bounds__(256) void gemm_mfma_bf16(const ushort* __restrict__ A,
                                                      const ushort* __restrict__ W,
                                                      const float* __restrict__ bias,
                                                      ushort* __restrict__ C,
                                                      int M) {
  __shared__ __align__(16) ushort As[64 * 256];
  __shared__ __align__(16) ushort Ws[64 * 256];

  const int t = threadIdx.x;
  const int w = t >> 6, l = t & 63;
  const int row0 = blockIdx.x * 64;
  const int col0 = blockIdx.y * 64;

  {
    const float4 zero4 = {0.f, 0.f, 0.f, 0.f};
#pragma unroll
    for (int i = 0; i < 8; ++i) {
      const int chunk = t + i * 256;
      const int r  = chunk >> 5;
      const int kb = (chunk & 31) << 4;
      const int swz = kb ^ ((r & 7) << 4);
      const int grow = row0 + r;
      float4 av = zero4;
      if (grow < M)
        av = *reinterpret_cast<const float4*>(
            reinterpret_cast<const char*>(A) + (size_t)grow * 512 + kb);
      *reinterpret_cast<float4*>(reinterpret_cast<char*>(As) + r * 512 + swz) = av;
      const float4 wv = *reinterpret_cast<const float4*>(
          reinterpret_cast<const char*>(W) + (size_t)(col0 + r) * 512 + kb);
      *reinterpret_cast<float4*>(reinterpret_cast<char*>(Ws) + r * 512 + swz) = wv;
    }
  }
  __syncthreads();

  const int g  = l >> 4;
  const int fr = l & 15;

  frag_cd acc[4];
#pragma unroll
  for (int c = 0; c < 4; ++c) {
    acc[c][0] = 0.f; acc[c][1] = 0.f; acc[c][2] = 0.f; acc[c][3] = 0.f;
  }

  const int arow = w * 16 + fr;
  const char* Asb = reinterpret_cast<const char*>(As);
  const char* Wsb = reinterpret_cast<const char*>(Ws);
#pragma unroll
  for (int ks = 0; ks < 8; ++ks) {
    const int kb = ks * 64 + g * 16;
    const frag_ab af = *reinterpret_cast<const frag_ab*>(
        Asb + arow * 512 + (kb ^ ((arow & 7) << 4)));
#pragma unroll
    for (int c = 0; c < 4; ++c) {
      const int wrow = c * 16 + fr;
      const frag_ab bf = *reinterpret_cast<const frag_ab*>(
          Wsb + wrow * 512 + (kb ^ ((wrow & 7) << 4)));
      acc[c] = __builtin_amdgcn_mfma_f32_16x16x32_bf16(af, bf, acc[c], 0, 0, 0);
    }
  }
  __syncthreads();

  ushort* Ct = As;
#pragma unroll
  for (int c = 0; c < 4; ++c) {
    const int col = c * 16 + fr;
    const float bv = bias[col0 + col];
#pragma unroll
    for (int r = 0; r < 4; ++r) {
      const int rl = w * 16 + g * 4 + r;
      Ct[rl * 64 + col] = f2bf(fmaxf(acc[c][r] + bv, 0.f));
    }
  }
  __syncthreads();
#pragma unroll
  for (int i = 0; i < 2; ++i) {
    const int chunk = t + i * 256;
    const int r  = chunk >> 3;
    const int cb = (chunk & 7) << 4;
    const int grow = row0 + r;
    if (grow < M)
      *reinterpret_cast<float4*>(reinterpret_cast<char*>(C) + (size_t)grow * 512 + col0 * 2 + cb) =
          *reinterpret_cast<const float4*>(reinterpret_cast<const char*>(Ct) + r * 128 + cb);
  }
}

// ---------------------------------------------------------------------------
// Pair head: one wave per 2 pairs; half-wave reads one h row each.
// ---------------------------------------------------------------------------
__global__ __launch_bounds__(256) void pair_head_bf16(const ushort* __restrict__ h,
                                                      const int* __restrict__ idx,
                                                      const float* __restrict__ W3,
                                                      const float* __restrict__ b3,
                                                      float* __restrict__ out) {
  const int wave = (int)((blockIdx.x * (size_t)blockDim.x + threadIdx.x) >> 6);
  const int lane = threadIdx.x & 63;
  const int half = lane >> 5;
  const int fl   = lane & 31;
  const int p0 = 2 * wave, p1 = 2 * wave + 1;
  if (p0 >= N_PAIRS) return;

  const int ia = idx[2 * p0 + half];
  const int ib = idx[2 * p1 + half];
  const ushort8 va = *reinterpret_cast<const ushort8*>(h + (size_t)ia * D + fl * 8);
  const ushort8 vb = *reinterpret_cast<const ushort8*>(h + (size_t)ib * D + fl * 8);

  const float4 w0a = *reinterpret_cast<const float4*>(W3 + lane * 8);
  const float4 w0b = *reinterpret_cast<const float4*>(W3 + lane * 8 + 4);
  const float4 w1a = *reinterpret_cast<const float4*>(W3 + 512 + lane * 8);
  const float4 w1b = *reinterpret_cast<const float4*>(W3 + 512 + lane * 8 + 4);
  const float w0[8] = {w0a.x, w0a.y, w0a.z, w0a.w, w0b.x, w0b.y, w0b.z, w0b.w};
  const float w1[8] = {w1a.x, w1a.y, w1a.z, w1a.w, w1b.x, w1b.y, w1b.z, w1b.w};

  float l00 = 0.f, l01 = 0.f, l10 = 0.f, l11 = 0.f;
#pragma unroll
  for (int j = 0; j < 8; ++j) {
    const float fa = b2f(va[j]), fb = b2f(vb[j]);
    l00 += fa * w0[j]; l01 += fa * w1[j];
    l10 += fb * w0[j]; l11 += fb * w1[j];
  }
#pragma unroll
  for (int off = 32; off > 0; off >>= 1) {
    l00 += __shfl_down(l00, off, 64);
    l01 += __shfl_down(l01, off, 64);
    l10 += __shfl_down(l10, off, 64);
    l11 += __shfl_down(l11, off, 64);
  }
  if (lane == 0) {
    const float bb0 = b3[0], bb1 = b3[1];
    l00 += bb0; l01 += bb1; l10 += bb0; l11 += bb1;
    const float m0 = fmaxf(l00, l01);
    const float lse0 = m0 + logf(expf(l00 - m0) + expf(l01 - m0));
    const float m1 = fmaxf(l10, l11);
    const float lse1 = m1 + logf(expf(l10 - m1) + expf(l11 - m1));
    float4 o;
    o.x = l00 - lse0; o.y = l01 - lse0; o.z = l10 - lse1; o.w = l11 - lse1;
    *reinterpret_cast<float4*>(out + 4 * (size_t)wave) = o;
  }
}

// ---------------------------------------------------------------------------
extern "C" void kernel_launch(void* const* d_in, const int* in_sizes, int n_in,
                              void* d_out, int out_size, void* d_ws, size_t ws_size,
                              hipStream_t stream) {
  const float* x   = (const float*)d_in[0];
  const int*   ei  = (const int*)d_in[1];
  const int*   idx = (const int*)d_in[2];
  const float* W1  = (const float*)d_in[3];
  const float* b1  = (const float*)d_in[4];
  const float* W2  = (const float*)d_in[5];
  const float* b2  = (const float*)d_in[6];
  const float* W3  = (const float*)d_in[7];
  const float* b3  = (const float*)d_in[8];
  float* out = (float*)d_out;

  char* ws = (char*)d_ws;
  // persistent buffers
  ushort* buf0 = (ushort*)(ws);                       // xb, then hb (51.2 MB)
  ushort* buf1 = (ushort*)(ws + 51200000);            // aggb (51.2 MB)
  ushort* W1b  = (ushort*)(ws + 102400000);           // 128 KB
  ushort* W2b  = (ushort*)(ws + 102531072);           // 128 KB
  int* p2s     = (int*)(ws + 102662144);              // (SEGN+1) ints = 6.42 MB
  int* csr     = (int*)(ws + 109084800);              // 12.8 MB  (ends ~121.9 MB)
  // build-time temporaries aliased into buf1 (dead before gather1 writes it)
  int* cnt     = (int*)(ws + 51200000);               // SEGN ints (6.42 MB)
  int* pos     = (int*)(ws + 51200000 + 8000000);     // SEGN ints
  int* bsum    = (int*)(ws + 51200000 + 16000000);    // 1568 ints
  int* bsum2   = (int*)(ws + 51200000 + 16100000);    // 1568 ints

  const dim3 blk(256);
  const size_t feat = (size_t)N_NODES * D;
  const dim3 edgeGrid((N_EDGES + 255) / 256);
  const int  nseg = (N_EDGES + FILL_SEG - 1) / FILL_SEG;
  const dim3 fillGrid(8 * nseg);
  const dim3 gemmGrid((N_NODES + 63) / 64, D / 64);
  const dim3 pairGrid(((size_t)(N_PAIRS / 2) * 64 + 255) / 256);
  constexpr int SCAN_BLOCKS = SEGN / 1024;   // 1568

  // ---- converts ----
  f32_to_bf16<<<dim3(4096), blk, 0, stream>>>((const float4*)x, (ushort4*)buf0, (int)(feat / 4));
  f32_to_bf16<<<dim3(64), blk, 0, stream>>>((const float4*)W1, (ushort4*)W1b, 65536 / 4);
  f32_to_bf16<<<dim3(64), blk, 0, stream>>>((const float4*)W2, (ushort4*)W2b, 65536 / 4);

  // ---- chunk-major CSR build ----
  zero_ints<<<dim3((SEGN + 255) / 256), blk, 0, stream>>>(cnt, SEGN);
  hist_cm_kernel<<<edgeGrid, blk, 0, stream>>>(ei, cnt);
  scan_block_k<<<dim3(SCAN_BLOCKS), dim3(1024), 0, stream>>>(cnt, p2s, bsum);
  scan_kernel<<<1, 1024, 0, stream>>>(bsum, bsum2, SCAN_BLOCKS);
  scan_add_k<<<dim3(SCAN_BLOCKS), dim3(1024), 0, stream>>>(p2s, bsum2);
  hipMemcpyAsync(pos, p2s, (size_t)SEGN * 4, hipMemcpyDeviceToDevice, stream);
  fill_cm_kernel<<<fillGrid, blk, 0, stream>>>(ei, pos, csr);

  // ---- phased gather launcher (coop if it fits, else same kernel w/o sync) ----
  int maxb = 0;
  hipError_t qe = hipOccupancyMaxActiveBlocksPerMultiprocessor(&maxb, gather_phased<true>, 256, 0);
  const bool coop_ok = (qe == hipSuccess) && (maxb >= 2);

  auto launch_gather = [&](const ushort* in, ushort* o) {
    if (coop_ok) {
      const ushort* a0 = in; const int* a1 = csr; const int* a2 = p2s; ushort* a3 = o;
      void* args[] = {(void*)&a0, (void*)&a1, (void*)&a2, (void*)&a3};
      hipError_t le = hipLaunchCooperativeKernel(gather_phased<true>,
                                                 dim3(GATHER_BLOCKS), dim3(256),
                                                 args, 0, stream);
      if (le == hipSuccess) return;
    }
    gather_phased<false><<<dim3(GATHER_BLOCKS), blk, 0, stream>>>(in, csr, p2s, o);
  };

  // ---- layer 1: buf0(x) -> buf1(agg) -> buf0(h1) ----
  launch_gather(buf0, buf1);
  gemm_mfma_bf16<<<gemmGrid, blk, 0, stream>>>(buf1, W1b, b1, buf0, N_NODES);

  // ---- layer 2: buf0(h1) -> buf1(agg2) -> buf0(h2) ----
  launch_gather(buf0, buf1);
  gemm_mfma_bf16<<<gemmGrid, blk, 0, stream>>>(buf1, W2b, b2, buf0, N_NODES);

  // ---- pair head ----
  pair_head_bf16<<<pairGrid, blk, 0, stream>>>(buf0, idx, W3, b3, out);
}